// Round 1
// baseline (338.562 us; speedup 1.0000x reference)
//
#include <hip/hip_runtime.h>
#include <hip/hip_bf16.h>

typedef __bf16 bf16x8 __attribute__((ext_vector_type(8)));
typedef float f32x4 __attribute__((ext_vector_type(4)));

#define BS   8192   // B*S rows
#define Hd   1024
#define LSd  2048
#define Md   64

static __device__ __forceinline__ float bfu2f(unsigned short u) {
  return __uint_as_float(((unsigned int)u) << 16);
}
static __device__ __forceinline__ __hip_bfloat16 f2bf(float f) { return __float2bfloat16(f); }

// ======================= prep kernels =======================

__global__ __launch_bounds__(256) void conv_bf16_kernel(const float* __restrict__ src,
    __hip_bfloat16* __restrict__ dst, int n) {
  int i = (blockIdx.x * 256 + threadIdx.x) * 4;
  if (i + 3 < n) {
    float4 f = *(const float4*)(src + i);
    dst[i + 0] = f2bf(f.x); dst[i + 1] = f2bf(f.y);
    dst[i + 2] = f2bf(f.z); dst[i + 3] = f2bf(f.w);
  }
}

// Wcat_t[512][1024]: n=0 decay, 1..128 key, 129..256 value, 257..320 ql, 321..384 qr, rest 0
__global__ __launch_bounds__(256) void prep_wcat_kernel(const float* __restrict__ Wd,
    const float* __restrict__ Wk, const float* __restrict__ Wv,
    const float* __restrict__ Wql, const float* __restrict__ Wqr,
    __hip_bfloat16* __restrict__ out) {
  int i = blockIdx.x * 256 + threadIdx.x;   // 512*1024 total
  int n = i >> 10, h = i & 1023;
  float v = 0.f;
  if (n == 0)        v = Wd[h];
  else if (n < 129)  v = Wk[h * 128 + (n - 1)];
  else if (n < 257)  v = Wv[h * 128 + (n - 129)];
  else if (n < 321)  v = Wql[h * 64 + (n - 257)];
  else if (n < 385)  v = Wqr[h * 64 + (n - 321)];
  out[i] = f2bf(v);
}

// dst[(c + c_off)][r] = (bf16) src[r][c];  src is R x C f32, dst leading dim = R
__global__ __launch_bounds__(256) void transpose_conv_kernel(const float* __restrict__ src,
    __hip_bfloat16* __restrict__ dst, int R, int C, int c_off) {
  __shared__ float tile[32][33];
  int bc = blockIdx.x * 32, br = blockIdx.y * 32;
  int tx = threadIdx.x & 31, ty = threadIdx.x >> 5;   // 32 x 8
  #pragma unroll
  for (int i = 0; i < 32; i += 8)
    tile[ty + i][tx] = src[(size_t)(br + ty + i) * C + bc + tx];
  __syncthreads();
  #pragma unroll
  for (int i = 0; i < 32; i += 8)
    dst[(size_t)(bc + c_off + ty + i) * R + br + tx] = f2bf(tile[tx][ty + i]);
}

// ======================= GEMM core =======================
// 128x128 tile, BK=32, 256 threads = 4 waves (2x2 of 64x64), mfma 16x16x32 bf16

static __device__ __forceinline__ void stage_tile(const __hip_bfloat16* __restrict__ src, int ld,
    __hip_bfloat16* __restrict__ dst, int tid) {
  #pragma unroll
  for (int it = 0; it < 2; ++it) {
    int idx = tid + it * 256;            // 0..511
    int r = idx >> 2, cc = (idx & 3) * 8; // 128 rows x 4 chunks of 8 bf16
    *(uint4*)(dst + r * 32 + cc) = *(const uint4*)(src + (size_t)r * ld + cc);
  }
}

static __device__ __forceinline__ void mfma_tiles(const __hip_bfloat16* sA, const __hip_bfloat16* sB,
    int wm, int wn, int fr, int qk, f32x4 acc[4][4]) {
  bf16x8 af[4], bg[4];
  #pragma unroll
  for (int i = 0; i < 4; ++i) af[i] = *(const bf16x8*)(sA + (wm + i * 16 + fr) * 32 + qk);
  #pragma unroll
  for (int j = 0; j < 4; ++j) bg[j] = *(const bf16x8*)(sB + (wn + j * 16 + fr) * 32 + qk);
  #pragma unroll
  for (int i = 0; i < 4; ++i)
    #pragma unroll
    for (int j = 0; j < 4; ++j)
      acc[i][j] = __builtin_amdgcn_mfma_f32_16x16x32_bf16(af[i], bg[j], acc[i][j], 0, 0, 0);
}

// proj = x_bf @ Wcat_t^T : C[8192][512] f32
__global__ __launch_bounds__(256, 2) void gemm_proj_kernel(const __hip_bfloat16* __restrict__ A,
    const __hip_bfloat16* __restrict__ Bt, float* __restrict__ C) {
  __shared__ __align__(16) __hip_bfloat16 sA[128 * 32];
  __shared__ __align__(16) __hip_bfloat16 sB[128 * 32];
  int tid = threadIdx.x, nb = blockIdx.x, mb = blockIdx.y;
  int wave = tid >> 6, lane = tid & 63;
  int wm = (wave >> 1) * 64, wn = (wave & 1) * 64;
  int fr = lane & 15, qk = (lane >> 4) * 8, q4 = (lane >> 4) * 4;
  f32x4 acc[4][4] = {};
  const __hip_bfloat16* Atile = A + (size_t)mb * 128 * Hd;
  const __hip_bfloat16* Btile = Bt + (size_t)nb * 128 * Hd;
  for (int kt = 0; kt < Hd; kt += 32) {
    __syncthreads();
    stage_tile(Atile + kt, Hd, sA, tid);
    stage_tile(Btile + kt, Hd, sB, tid);
    __syncthreads();
    mfma_tiles(sA, sB, wm, wn, fr, qk, acc);
  }
  #pragma unroll
  for (int i = 0; i < 4; ++i)
    #pragma unroll
    for (int j = 0; j < 4; ++j) {
      int row = mb * 128 + wm + i * 16 + q4;
      int col = nb * 128 + wn + j * 16 + fr;
      #pragma unroll
      for (int rg = 0; rg < 4; ++rg)
        C[(size_t)(row + rg) * 512 + col] = acc[i][j][rg];
    }
}

// h = (x@W_up) * silu(x@W_gate), bf16 out, dual accumulators sharing A tile
__global__ __launch_bounds__(256, 2) void gemm_upgate_kernel(const __hip_bfloat16* __restrict__ A,
    const __hip_bfloat16* __restrict__ Bt, __hip_bfloat16* __restrict__ hout) {
  __shared__ __align__(16) __hip_bfloat16 sA[128 * 32];
  __shared__ __align__(16) __hip_bfloat16 sBu[128 * 32];
  __shared__ __align__(16) __hip_bfloat16 sBg[128 * 32];
  int tid = threadIdx.x, nb = blockIdx.x, mb = blockIdx.y;
  int wave = tid >> 6, lane = tid & 63;
  int wm = (wave >> 1) * 64, wn = (wave & 1) * 64;
  int fr = lane & 15, qk = (lane >> 4) * 8, q4 = (lane >> 4) * 4;
  f32x4 accu[4][4] = {}, accg[4][4] = {};
  const __hip_bfloat16* Atile = A + (size_t)mb * 128 * Hd;
  const __hip_bfloat16* Bu = Bt + (size_t)(nb * 128) * Hd;
  const __hip_bfloat16* Bg = Bt + (size_t)(2048 + nb * 128) * Hd;
  for (int kt = 0; kt < Hd; kt += 32) {
    __syncthreads();
    stage_tile(Atile + kt, Hd, sA, tid);
    stage_tile(Bu + kt, Hd, sBu, tid);
    stage_tile(Bg + kt, Hd, sBg, tid);
    __syncthreads();
    mfma_tiles(sA, sBu, wm, wn, fr, qk, accu);
    mfma_tiles(sA, sBg, wm, wn, fr, qk, accg);
  }
  #pragma unroll
  for (int i = 0; i < 4; ++i)
    #pragma unroll
    for (int j = 0; j < 4; ++j) {
      int col = nb * 128 + wn + j * 16 + fr;
      #pragma unroll
      for (int rg = 0; rg < 4; ++rg) {
        int row = mb * 128 + wm + i * 16 + q4 + rg;
        float u = accu[i][j][rg], g = accg[i][j][rg];
        float hv = u * g / (1.f + __expf(-g));
        hout[(size_t)row * LSd + col] = f2bf(hv);
      }
    }
}

// out = h@Wdown_t^T + Rd@Wrec_t^T  (K = 2048 then 64), f32 out
__global__ __launch_bounds__(256, 2) void gemm_final_kernel(const __hip_bfloat16* __restrict__ A,
    const __hip_bfloat16* __restrict__ Bt, const __hip_bfloat16* __restrict__ A2,
    const __hip_bfloat16* __restrict__ B2t, float* __restrict__ C) {
  __shared__ __align__(16) __hip_bfloat16 sA[128 * 32];
  __shared__ __align__(16) __hip_bfloat16 sB[128 * 32];
  int tid = threadIdx.x, nb = blockIdx.x, mb = blockIdx.y;
  int wave = tid >> 6, lane = tid & 63;
  int wm = (wave >> 1) * 64, wn = (wave & 1) * 64;
  int fr = lane & 15, qk = (lane >> 4) * 8, q4 = (lane >> 4) * 4;
  f32x4 acc[4][4] = {};
  const __hip_bfloat16* Atile = A + (size_t)mb * 128 * LSd;
  const __hip_bfloat16* Btile = Bt + (size_t)nb * 128 * LSd;
  for (int kt = 0; kt < LSd; kt += 32) {
    __syncthreads();
    stage_tile(Atile + kt, LSd, sA, tid);
    stage_tile(Btile + kt, LSd, sB, tid);
    __syncthreads();
    mfma_tiles(sA, sB, wm, wn, fr, qk, acc);
  }
  const __hip_bfloat16* A2t = A2 + (size_t)mb * 128 * Md;
  const __hip_bfloat16* B2tile = B2t + (size_t)nb * 128 * Md;
  for (int kt = 0; kt < Md; kt += 32) {
    __syncthreads();
    stage_tile(A2t + kt, Md, sA, tid);
    stage_tile(B2tile + kt, Md, sB, tid);
    __syncthreads();
    mfma_tiles(sA, sB, wm, wn, fr, qk, acc);
  }
  #pragma unroll
  for (int i = 0; i < 4; ++i)
    #pragma unroll
    for (int j = 0; j < 4; ++j) {
      int row = mb * 128 + wm + i * 16 + q4;
      int col = nb * 128 + wn + j * 16 + fr;
      #pragma unroll
      for (int rg = 0; rg < 4; ++rg)
        C[(size_t)(row + rg) * Hd + col] = acc[i][j][rg];
    }
}

// ======================= recurrent (chunked gated linear attention) =======================
// chunk C=64. proj row layout: [0]=z_decay, [1..129)=key(r*64+m), [129..257)=value, [257..321)=ql, [321..385)=qr

__global__ __launch_bounds__(256) void scan_chunk_kernel(const float* __restrict__ proj,
    float* __restrict__ Lam, float* __restrict__ udv, float* __restrict__ alpha,
    float* __restrict__ dS) {
  int bc = blockIdx.x, t0 = bc * 64, tid = threadIdx.x;
  __shared__ float d_s[64], ld_s[64], Lam_s[64], u_s[64];
  __shared__ __align__(16) __hip_bfloat16 k_s[128 * 64];
  __shared__ __align__(16) __hip_bfloat16 v_s[128 * 64];
  if (tid < 64) {
    float z = proj[(size_t)(t0 + tid) * 512];
    float dd = 1.f / (1.f + __expf(-z));
    float l = (z >= 0.f) ? -log1pf(__expf(-z)) : (z - log1pf(__expf(z)));
    d_s[tid] = dd; ld_s[tid] = l;
  }
  __syncthreads();
  if (tid == 0) {
    float s = 0.f;
    for (int j = 0; j < 64; ++j) { s += ld_s[j]; Lam_s[j] = s; }
  }
  __syncthreads();
  float Lend = Lam_s[63];
  if (tid < 64) {
    u_s[tid] = (1.f - d_s[tid]) * __expf(Lend - Lam_s[tid]) * 0.5f;  // includes 1/R
    Lam[t0 + tid] = Lam_s[tid];
    udv[t0 + tid] = (1.f - d_s[tid]) * 0.5f;                          // includes 1/R
  }
  if (tid == 0) alpha[bc] = __expf(Lend);
  __syncthreads();
  for (int i = tid; i < 128 * 64; i += 256) {
    int jr = i >> 6, m = i & 63, j = jr >> 1, r = jr & 1;
    const float* rowp = proj + (size_t)(t0 + j) * 512;
    k_s[i] = f2bf(u_s[j] * rowp[1 + r * 64 + m]);
    v_s[i] = f2bf(rowp[129 + r * 64 + m]);
  }
  __syncthreads();
  int m0 = (tid & 15) * 4, n0 = (tid >> 4) * 4;
  float acc[4][4] = {{0.f}};
  for (int jr = 0; jr < 128; ++jr) {
    ushort4 ku = *(const ushort4*)&k_s[jr * 64 + m0];
    ushort4 vu = *(const ushort4*)&v_s[jr * 64 + n0];
    float k0 = bfu2f(ku.x), k1 = bfu2f(ku.y), k2 = bfu2f(ku.z), k3 = bfu2f(ku.w);
    float v0 = bfu2f(vu.x), v1 = bfu2f(vu.y), v2 = bfu2f(vu.z), v3 = bfu2f(vu.w);
    acc[0][0] += k0 * v0; acc[0][1] += k0 * v1; acc[0][2] += k0 * v2; acc[0][3] += k0 * v3;
    acc[1][0] += k1 * v0; acc[1][1] += k1 * v1; acc[1][2] += k1 * v2; acc[1][3] += k1 * v3;
    acc[2][0] += k2 * v0; acc[2][1] += k2 * v1; acc[2][2] += k2 * v2; acc[2][3] += k2 * v3;
    acc[3][0] += k3 * v0; acc[3][1] += k3 * v1; acc[3][2] += k3 * v2; acc[3][3] += k3 * v3;
  }
  float* outp = dS + (size_t)bc * 4096;
  #pragma unroll
  for (int a = 0; a < 4; ++a)
    #pragma unroll
    for (int b2 = 0; b2 < 4; ++b2)
      outp[(m0 + a) * 64 + (n0 + b2)] = acc[a][b2];
}

__global__ __launch_bounds__(256) void scan_cross_kernel(const float* __restrict__ dS,
    const float* __restrict__ alpha, const float* __restrict__ init_state,
    float* __restrict__ Sin) {
  int idx = blockIdx.x * 256 + threadIdx.x;   // 4 batches * 4096 elems
  int b = idx >> 12, e = idx & 4095;
  float s = init_state[e];
  for (int c = 0; c < 32; ++c) {
    int bc = b * 32 + c;
    Sin[(size_t)bc * 4096 + e] = s;
    s = alpha[bc] * s + dS[(size_t)bc * 4096 + e];
  }
}

#define QLD 68   // padded leading dim for ql tile (keeps 8B alignment, breaks bank stride)

__global__ __launch_bounds__(256) void scan_read_kernel(const float* __restrict__ proj,
    const float* __restrict__ Lam, const float* __restrict__ udv,
    const float* __restrict__ Sin, __hip_bfloat16* __restrict__ Rd) {
  int bc = blockIdx.x, t0 = bc * 64, tid = threadIdx.x;
  __shared__ __align__(16) __hip_bfloat16 ql_s[64 * QLD];
  __shared__ __align__(16) __hip_bfloat16 kv_s[128 * 64];   // K then V
  __shared__ __align__(16) __hip_bfloat16 S_s[64 * 64];
  __shared__ __align__(16) __hip_bfloat16 P_s[128 * 64];    // [jr][t]
  __shared__ float Lam_s[64], ud_s[64], eL_s[64];
  for (int i = tid; i < 64 * 64; i += 256) {
    int t = i >> 6, m = i & 63;
    ql_s[t * QLD + m] = f2bf(proj[(size_t)(t0 + t) * 512 + 257 + m]);
    S_s[i] = f2bf(Sin[(size_t)bc * 4096 + i]);
  }
  for (int i = tid; i < 128 * 64; i += 256) {
    int jr = i >> 6, m = i & 63, j = jr >> 1, r = jr & 1;
    kv_s[i] = f2bf(proj[(size_t)(t0 + j) * 512 + 1 + r * 64 + m]);
  }
  if (tid < 64) {
    float L = Lam[t0 + tid];
    Lam_s[tid] = L; ud_s[tid] = udv[t0 + tid]; eL_s[tid] = __expf(L);
  }
  __syncthreads();
  int tr = (tid & 15) * 4, n0 = (tid >> 4) * 4;
  float acc[4][4] = {{0.f}};
  // cross term: e^{Lam_t} * (ql_t @ S_in)
  for (int mb4 = 0; mb4 < 64; mb4 += 4) {
    float sm[4][4];
    #pragma unroll
    for (int mm = 0; mm < 4; ++mm) {
      ushort4 sv = *(const ushort4*)&S_s[(mb4 + mm) * 64 + n0];
      sm[mm][0] = bfu2f(sv.x); sm[mm][1] = bfu2f(sv.y);
      sm[mm][2] = bfu2f(sv.z); sm[mm][3] = bfu2f(sv.w);
    }
    #pragma unroll
    for (int a = 0; a < 4; ++a) {
      ushort4 qa = *(const ushort4*)&ql_s[(tr + a) * QLD + mb4];
      float q0 = bfu2f(qa.x), q1 = bfu2f(qa.y), q2 = bfu2f(qa.z), q3 = bfu2f(qa.w);
      #pragma unroll
      for (int b2 = 0; b2 < 4; ++b2)
        acc[a][b2] += q0 * sm[0][b2] + q1 * sm[1][b2] + q2 * sm[2][b2] + q3 * sm[3][b2];
    }
  }
  #pragma unroll
  for (int a = 0; a < 4; ++a) {
    float e = eL_s[tr + a];
    #pragma unroll
    for (int b2 = 0; b2 < 4; ++b2) acc[a][b2] *= e;
  }
  // intra-chunk scores P[jr][t] = coef(t,j) * (ql_t . k_jr)
  {
    int jr = tid >> 1, j = jr >> 1, tb = (tid & 1) * 32;
    float dot[32];
    #pragma unroll
    for (int t2 = 0; t2 < 32; ++t2) dot[t2] = 0.f;
    for (int m = 0; m < 64; m += 4) {
      ushort4 kb = *(const ushort4*)&kv_s[jr * 64 + m];
      float k0 = bfu2f(kb.x), k1 = bfu2f(kb.y), k2 = bfu2f(kb.z), k3 = bfu2f(kb.w);
      #pragma unroll
      for (int t2 = 0; t2 < 32; ++t2) {
        ushort4 qa = *(const ushort4*)&ql_s[(tb + t2) * QLD + m];
        dot[t2] += bfu2f(qa.x) * k0 + bfu2f(qa.y) * k1 + bfu2f(qa.z) * k2 + bfu2f(qa.w) * k3;
      }
    }
    #pragma unroll
    for (int t2 = 0; t2 < 32; ++t2) {
      int t = tb + t2;
      float coef = (j <= t) ? ud_s[j] * __expf(Lam_s[t] - Lam_s[j]) : 0.f;
      P_s[jr * 64 + t] = f2bf(dot[t2] * coef);
    }
  }
  __syncthreads();
  for (int i = tid; i < 128 * 64; i += 256) {    // reload V over K
    int jr = i >> 6, m = i & 63, j = jr >> 1, r = jr & 1;
    kv_s[i] = f2bf(proj[(size_t)(t0 + j) * 512 + 129 + r * 64 + m]);
  }
  __syncthreads();
  for (int jr = 0; jr < 128; ++jr) {
    ushort4 pu = *(const ushort4*)&P_s[jr * 64 + tr];
    ushort4 vu = *(const ushort4*)&kv_s[jr * 64 + n0];
    float p0 = bfu2f(pu.x), p1 = bfu2f(pu.y), p2 = bfu2f(pu.z), p3 = bfu2f(pu.w);
    float v0 = bfu2f(vu.x), v1 = bfu2f(vu.y), v2 = bfu2f(vu.z), v3 = bfu2f(vu.w);
    acc[0][0] += p0 * v0; acc[0][1] += p0 * v1; acc[0][2] += p0 * v2; acc[0][3] += p0 * v3;
    acc[1][0] += p1 * v0; acc[1][1] += p1 * v1; acc[1][2] += p1 * v2; acc[1][3] += p1 * v3;
    acc[2][0] += p2 * v0; acc[2][1] += p2 * v1; acc[2][2] += p2 * v2; acc[2][3] += p2 * v3;
    acc[3][0] += p3 * v0; acc[3][1] += p3 * v1; acc[3][2] += p3 * v2; acc[3][3] += p3 * v3;
  }
  // qr gate + silu + store
  #pragma unroll
  for (int a = 0; a < 4; ++a) {
    int t = t0 + tr + a;
    const float* qrp = proj + (size_t)t * 512 + 321;
    #pragma unroll
    for (int b2 = 0; b2 < 4; ++b2) {
      float rv = acc[a][b2] * qrp[n0 + b2];
      float sv = rv / (1.f + __expf(-rv));
      Rd[(size_t)t * 64 + n0 + b2] = f2bf(sv);
    }
  }
}

// ======================= launch =======================

extern "C" void kernel_launch(void* const* d_in, const int* in_sizes, int n_in,
                              void* d_out, int out_size, void* d_ws, size_t ws_size,
                              hipStream_t stream) {
  const float* x      = (const float*)d_in[0];
  const float* W_dec  = (const float*)d_in[1];
  const float* W_key  = (const float*)d_in[2];
  const float* W_val  = (const float*)d_in[3];
  const float* W_ql   = (const float*)d_in[4];
  const float* W_qr   = (const float*)d_in[5];
  const float* W_rec  = (const float*)d_in[6];
  const float* W_up   = (const float*)d_in[7];
  const float* W_gate = (const float*)d_in[8];
  const float* W_down = (const float*)d_in[9];
  const float* init_state = (const float*)d_in[10];
  float* out = (float*)d_out;

  char* w = (char*)d_ws;
  auto take = [&](size_t bytes) { char* p = w; w += (bytes + 255) & ~(size_t)255; return p; };
  __hip_bfloat16* x_bf   = (__hip_bfloat16*)take((size_t)BS * Hd * 2);
  __hip_bfloat16* Wcat_t = (__hip_bfloat16*)take((size_t)512 * Hd * 2);
  __hip_bfloat16* Wug_t  = (__hip_bfloat16*)take((size_t)4096 * Hd * 2);
  __hip_bfloat16* Wdn_t  = (__hip_bfloat16*)take((size_t)Hd * LSd * 2);
  __hip_bfloat16* Wrc_t  = (__hip_bfloat16*)take((size_t)Hd * Md * 2);
  float* proj  = (float*)take((size_t)BS * 512 * 4);
  float* Lam   = (float*)take((size_t)BS * 4);
  float* udv   = (float*)take((size_t)BS * 4);
  float* alpha = (float*)take((size_t)128 * 4);
  float* dS    = (float*)take((size_t)128 * 4096 * 4);
  float* Sin   = (float*)take((size_t)128 * 4096 * 4);
  __hip_bfloat16* Rd   = (__hip_bfloat16*)take((size_t)BS * Md * 2);
  __hip_bfloat16* hbuf = (__hip_bfloat16*)take((size_t)BS * LSd * 2);

  conv_bf16_kernel<<<8192, 256, 0, stream>>>(x, x_bf, BS * Hd);
  prep_wcat_kernel<<<2048, 256, 0, stream>>>(W_dec, W_key, W_val, W_ql, W_qr, Wcat_t);
  transpose_conv_kernel<<<dim3(64, 32), 256, 0, stream>>>(W_up,   Wug_t, Hd, LSd, 0);
  transpose_conv_kernel<<<dim3(64, 32), 256, 0, stream>>>(W_gate, Wug_t, Hd, LSd, 2048);
  transpose_conv_kernel<<<dim3(32, 64), 256, 0, stream>>>(W_down, Wdn_t, LSd, Hd, 0);
  transpose_conv_kernel<<<dim3(32, 2),  256, 0, stream>>>(W_rec,  Wrc_t, Md, Hd, 0);

  gemm_proj_kernel<<<dim3(4, 64), 256, 0, stream>>>(x_bf, Wcat_t, proj);

  scan_chunk_kernel<<<128, 256, 0, stream>>>(proj, Lam, udv, alpha, dS);
  scan_cross_kernel<<<64, 256, 0, stream>>>(dS, alpha, init_state, Sin);
  scan_read_kernel<<<128, 256, 0, stream>>>(proj, Lam, udv, Sin, Rd);

  gemm_upgate_kernel<<<dim3(16, 64), 256, 0, stream>>>(x_bf, Wug_t, hbuf);
  gemm_final_kernel<<<dim3(8, 64), 256, 0, stream>>>(hbuf, Wdn_t, Rd, Wrc_t, out);
}